// Round 8
// baseline (1702.005 us; speedup 1.0000x reference)
//
#include <hip/hip_runtime.h>
#include <hip/hip_fp16.h>
#include <math.h>

#define N_MEMBERS 2
#define N_NODES   65536
#define N_EDGES   1048576
#define N_LAYERS  12
#define D         64
#define OFF_STRIDE (N_NODES + 1)
#define NODE_MASK (N_NODES - 1)

typedef _Float16 f16;
typedef f16   f16x8 __attribute__((ext_vector_type(8)));
typedef float f32x4 __attribute__((ext_vector_type(4)));
typedef int   i32x2 __attribute__((ext_vector_type(2)));

// ---------- preprocessing ----------

__global__ __launch_bounds__(256) void count_deg_k(const int* __restrict__ ei,
                                                   int* __restrict__ deg) {
    int e = blockIdx.x * 256 + threadIdx.x;
    int m = blockIdx.y;
    int dst = ei[(size_t)(m * 2 + 1) * N_EDGES + e] & NODE_MASK;
    atomicAdd(&deg[m * N_NODES + dst], 1);
}

__global__ __launch_bounds__(256) void dinv_k(const int* __restrict__ deg,
                                              float* __restrict__ dinv) {
    int i = blockIdx.x * 256 + threadIdx.x;   // over 2*N_NODES
    dinv[i] = 1.0f / sqrtf((float)deg[i] + 1.0f);
}

// ---- parallel 2-level exclusive scan of deg -> off ----
__global__ __launch_bounds__(256) void blocksum_k(const int* __restrict__ deg,
                                                  int* __restrict__ bs) {
    int m = blockIdx.y, blk = blockIdx.x, t = threadIdx.x;
    __shared__ int sh[256];
    sh[t] = deg[m * N_NODES + blk * 256 + t];
    __syncthreads();
    for (int ofs = 128; ofs > 0; ofs >>= 1) {
        if (t < ofs) sh[t] += sh[t + ofs];
        __syncthreads();
    }
    if (t == 0) bs[m * 256 + blk] = sh[0];
}

__global__ __launch_bounds__(256) void scan_bs_k(int* __restrict__ bs) {
    int m = blockIdx.x, t = threadIdx.x;
    __shared__ int sh[256];
    sh[t] = bs[m * 256 + t];
    __syncthreads();
    for (int ofs = 1; ofs < 256; ofs <<= 1) {
        int v = sh[t];
        int a = (t >= ofs) ? sh[t - ofs] : 0;
        __syncthreads();
        sh[t] = v + a;
        __syncthreads();
    }
    bs[m * 256 + t] = (t == 0) ? 0 : sh[t - 1];   // exclusive
}

__global__ __launch_bounds__(256) void scan_off_k(const int* __restrict__ deg,
                                                  const int* __restrict__ bs,
                                                  int* __restrict__ off) {
    int m = blockIdx.y, blk = blockIdx.x, t = threadIdx.x;
    int i = blk * 256 + t;
    int d = deg[m * N_NODES + i];
    __shared__ int sh[256];
    sh[t] = d;
    __syncthreads();
    for (int ofs = 1; ofs < 256; ofs <<= 1) {
        int v = sh[t];
        int a = (t >= ofs) ? sh[t - ofs] : 0;
        __syncthreads();
        sh[t] = v + a;
        __syncthreads();
    }
    off[m * OFF_STRIDE + i] = bs[m * 256 + blk] + sh[t] - d;  // exclusive
    if (i == N_NODES - 1) off[m * OFF_STRIDE + N_NODES] = N_EDGES;
}

// ---- CSR fill: one combined 8B (src, norm) store per edge ----
__global__ __launch_bounds__(256) void fill_k(const int* __restrict__ ei,
                                              const int* __restrict__ off,
                                              int* __restrict__ cursor,
                                              const float* __restrict__ dinv,
                                              int2* __restrict__ csr_es) {
    int e = blockIdx.x * 256 + threadIdx.x;
    int m = blockIdx.y;
    int src = ei[(size_t)(m * 2 + 0) * N_EDGES + e] & NODE_MASK;
    int dst = ei[(size_t)(m * 2 + 1) * N_EDGES + e] & NODE_MASK;
    int pos = off[m * OFF_STRIDE + dst] + atomicAdd(&cursor[m * N_NODES + dst], 1);
    float nrm = dinv[m * N_NODES + src] * dinv[m * N_NODES + dst];
    csr_es[(size_t)m * N_EDGES + pos] = make_int2(src, __float_as_int(nrm));
}

// ---------- per-layer GEMM via MFMA, split-fp16; planar fp16 output ----------
// hw layout: [member][plane(2)][node][32] fp16 (plane p = features p*32..p*32+31)
__device__ __forceinline__ void split8(const float* p, f16x8& hi, f16x8& lo) {
    float4 a = *(const float4*)p;
    float4 b = *(const float4*)(p + 4);
    float v[8] = {a.x, a.y, a.z, a.w, b.x, b.y, b.z, b.w};
    #pragma unroll
    for (int i = 0; i < 8; i++) {
        f16 h = (f16)v[i];
        hi[i] = h;
        lo[i] = (f16)(v[i] - (float)h);
    }
}

__global__ __launch_bounds__(256) void gemm_mfma_k(const float* __restrict__ h,
                                                   const float* __restrict__ Wall,
                                                   __half* __restrict__ hw, int layer) {
    int m = blockIdx.y;
    const float* Wg = Wall + (size_t)(m * N_LAYERS + layer) * D * D;
    __shared__ __align__(16) _Float16 Whi[D][72];
    __shared__ __align__(16) _Float16 Wlo[D][72];
    for (int idx = threadIdx.x; idx < D * D / 4; idx += 256) {
        float4 v = ((const float4*)Wg)[idx];
        int k  = idx >> 4;
        int c0 = (idx & 15) << 2;
        float vv[4] = {v.x, v.y, v.z, v.w};
        #pragma unroll
        for (int i = 0; i < 4; i++) {
            f16 hi = (f16)vv[i];
            Whi[c0 + i][k] = hi;
            Wlo[c0 + i][k] = (f16)(vv[i] - (float)hi);
        }
    }
    __syncthreads();

    int lane = threadIdx.x & 63;
    int wav  = threadIdx.x >> 6;
    int nn   = lane & 15;
    int quad = lane >> 4;

    f16x8 Bh[8], Bl[8];
    #pragma unroll
    for (int t = 0; t < 4; t++)
        #pragma unroll
        for (int s = 0; s < 2; s++) {
            Bh[t * 2 + s] = *(const f16x8*)&Whi[t * 16 + nn][s * 32 + quad * 8];
            Bl[t * 2 + s] = *(const f16x8*)&Wlo[t * 16 + nn][s * 32 + quad * 8];
        }

    const float* hm = h + (size_t)m * N_NODES * D;
    int base = blockIdx.x * 256 + wav * 64;
    for (int g = 0; g < 4; g++) {
        int n0 = base + g * 16;
        const float* hrow = hm + (size_t)(n0 + nn) * D;
        f16x8 ah[2], al[2];
        split8(hrow + quad * 8,      ah[0], al[0]);
        split8(hrow + 32 + quad * 8, ah[1], al[1]);
        #pragma unroll
        for (int t = 0; t < 4; t++) {
            f32x4 c = {0.f, 0.f, 0.f, 0.f};
            #pragma unroll
            for (int s = 0; s < 2; s++) {
                c = __builtin_amdgcn_mfma_f32_16x16x32_f16(ah[s], Bh[t*2+s], c, 0, 0, 0);
                c = __builtin_amdgcn_mfma_f32_16x16x32_f16(al[s], Bh[t*2+s], c, 0, 0, 0);
                c = __builtin_amdgcn_mfma_f32_16x16x32_f16(ah[s], Bl[t*2+s], c, 0, 0, 0);
            }
            int plane = t >> 1;
            int col   = (t & 1) * 16 + nn;
            __half* op = hw + ((size_t)(m * 2 + plane)) * N_NODES * 32;
            #pragma unroll
            for (int r = 0; r < 4; r++)
                op[(size_t)(n0 + quad * 4 + r) * 32 + col] = __float2half((float)c[r]);
        }
    }
}

// ---------- per-layer aggregate: planar, 8 edges per gather instruction ------
// plane = blockIdx.x & 1 (XCD round-robin affinity). lane = sub(3b)|fg(3b):
// fg = lane&7 (4 features), sub = lane>>3 (edge within group of 8).
__device__ __forceinline__ float4 cvt4(ushort4 u) {
    union { ushort2 us[2]; __half2 h2[2]; } c;
    c.us[0] = make_ushort2(u.x, u.y);
    c.us[1] = make_ushort2(u.z, u.w);
    float2 a = __half22float2(c.h2[0]);
    float2 b = __half22float2(c.h2[1]);
    return make_float4(a.x, a.y, b.x, b.y);
}

__global__ __launch_bounds__(256) void aggregate_k(const __half* __restrict__ hw,
                                                   float* __restrict__ out,
                                                   const int* __restrict__ off,
                                                   const int2* __restrict__ csr_es,
                                                   const float* __restrict__ dinv,
                                                   const float* __restrict__ ball,
                                                   int layer, int relu) {
    int m     = blockIdx.y;
    int plane = blockIdx.x & 1;
    int n     = (blockIdx.x >> 1) * 4 + (threadIdx.x >> 6);
    int lane  = threadIdx.x & 63;
    int fg    = lane & 7;
    int sub   = lane >> 3;
    const ushort4* hp = (const ushort4*)(hw + ((size_t)(m * 2 + plane)) * N_NODES * 32);
    const int*     ob = off + m * OFF_STRIDE;
    const i32x2*   eb = (const i32x2*)(csr_es + (size_t)m * N_EDGES);

    float4 acc = make_float4(0.f, 0.f, 0.f, 0.f);
    int e0 = ob[n], e1 = ob[n + 1];
    #pragma unroll 2
    for (int e = e0; e < e1; e += 8) {
        int ee  = e + sub;
        int idx = (ee < e1) ? ee : (e1 - 1);
        i32x2 p = __builtin_nontemporal_load(eb + idx);
        float w = (ee < e1) ? __int_as_float(p.y) : 0.0f;
        float4 g = cvt4(hp[(size_t)p.x * 8 + fg]);
        acc.x = fmaf(w, g.x, acc.x);
        acc.y = fmaf(w, g.y, acc.y);
        acc.z = fmaf(w, g.z, acc.z);
        acc.w = fmaf(w, g.w, acc.w);
    }
    #pragma unroll
    for (int msk = 8; msk < 64; msk <<= 1) {
        acc.x += __shfl_xor(acc.x, msk);
        acc.y += __shfl_xor(acc.y, msk);
        acc.z += __shfl_xor(acc.z, msk);
        acc.w += __shfl_xor(acc.w, msk);
    }

    float dv  = dinv[m * N_NODES + n];
    float dv2 = dv * dv;
    float4 s  = cvt4(hp[(size_t)n * 8 + fg]);
    float4 bi = ((const float4*)(ball + (size_t)(m * N_LAYERS + layer) * D + plane * 32))[fg];
    acc.x = fmaf(dv2, s.x, acc.x) + bi.x;
    acc.y = fmaf(dv2, s.y, acc.y) + bi.y;
    acc.z = fmaf(dv2, s.z, acc.z) + bi.z;
    acc.w = fmaf(dv2, s.w, acc.w) + bi.w;
    if (relu) {
        acc.x = fmaxf(acc.x, 0.f);
        acc.y = fmaxf(acc.y, 0.f);
        acc.z = fmaxf(acc.z, 0.f);
        acc.w = fmaxf(acc.w, 0.f);
    }
    if (lane < 8) {
        f32x4* o4 = (f32x4*)(out + (size_t)m * N_NODES * D + (size_t)n * D + plane * 32);
        f32x4 v = {acc.x, acc.y, acc.z, acc.w};
        __builtin_nontemporal_store(v, o4 + lane);
    }
}

// ---------- host ----------

extern "C" void kernel_launch(void* const* d_in, const int* in_sizes, int n_in,
                              void* d_out, int out_size, void* d_ws, size_t ws_size,
                              hipStream_t stream) {
    (void)in_sizes; (void)n_in; (void)out_size; (void)ws_size;
    const float* x  = (const float*)d_in[0];
    const int*   ei = (const int*)d_in[1];
    const float* W  = (const float*)d_in[2];
    const float* b  = (const float*)d_in[3];
    float* out = (float*)d_out;

    char* ws = (char*)d_ws;
    size_t o = 0;
    auto take = [&](size_t bytes) -> void* {
        void* p = ws + o;
        o = (o + bytes + 255) & ~(size_t)255;
        return p;
    };
    int*    deg      = (int*)   take((size_t)N_MEMBERS * N_NODES * 4);
    int*    cursor   = (int*)   take((size_t)N_MEMBERS * N_NODES * 4);
    float*  dinv     = (float*) take((size_t)N_MEMBERS * N_NODES * 4);
    int*    off      = (int*)   take((size_t)N_MEMBERS * OFF_STRIDE * 4);
    int*    bs       = (int*)   take((size_t)N_MEMBERS * 256 * 4);
    int2*   csr_es   = (int2*)  take((size_t)N_MEMBERS * N_EDGES * 8);
    __half* tbuf     = (__half*)take((size_t)N_MEMBERS * 2 * N_NODES * 32 * 2);
    float*  hbuf     = (float*) take((size_t)N_MEMBERS * N_NODES * D * 4);

    // zero deg + cursor (adjacent, both 256-padded)
    hipMemsetAsync(deg, 0, 2 * (size_t)N_MEMBERS * N_NODES * 4, stream);

    count_deg_k<<<dim3(N_EDGES / 256, N_MEMBERS), 256, 0, stream>>>(ei, deg);
    dinv_k<<<dim3((N_MEMBERS * N_NODES) / 256), 256, 0, stream>>>(deg, dinv);
    blocksum_k<<<dim3(N_NODES / 256, N_MEMBERS), 256, 0, stream>>>(deg, bs);
    scan_bs_k<<<dim3(N_MEMBERS), 256, 0, stream>>>(bs);
    scan_off_k<<<dim3(N_NODES / 256, N_MEMBERS), 256, 0, stream>>>(deg, bs, off);
    fill_k<<<dim3(N_EDGES / 256, N_MEMBERS), 256, 0, stream>>>(ei, off, cursor, dinv, csr_es);

    const float* hin = x;
    for (int j = 0; j < N_LAYERS; j++) {
        gemm_mfma_k<<<dim3(N_NODES / 256, N_MEMBERS), 256, 0, stream>>>(hin, W, tbuf, j);
        float* dst = (j == N_LAYERS - 1) ? out : hbuf;
        aggregate_k<<<dim3((N_NODES / 4) * 2, N_MEMBERS), 256, 0, stream>>>(
            tbuf, dst, off, csr_es, dinv, b, j, (j < N_LAYERS - 1) ? 1 : 0);
        hin = hbuf;
    }
}

// Round 9
// 1130.885 us; speedup vs baseline: 1.5050x; 1.5050x over previous
//
#include <hip/hip_runtime.h>
#include <hip/hip_fp16.h>
#include <math.h>

#define N_MEMBERS 2
#define N_NODES   65536
#define N_EDGES   1048576
#define N_LAYERS  12
#define D         64
#define OFF_STRIDE (N_NODES + 1)
#define NODE_MASK (N_NODES - 1)

typedef _Float16 f16;
typedef f16   f16x8 __attribute__((ext_vector_type(8)));
typedef float f32x4 __attribute__((ext_vector_type(4)));

// ---------- preprocessing ----------

__global__ __launch_bounds__(256) void count_deg_k(const int* __restrict__ ei,
                                                   int* __restrict__ deg) {
    int e = blockIdx.x * 256 + threadIdx.x;
    int m = blockIdx.y;
    int dst = ei[(size_t)(m * 2 + 1) * N_EDGES + e] & NODE_MASK;
    atomicAdd(&deg[m * N_NODES + dst], 1);
}

__global__ __launch_bounds__(256) void dinv_k(const int* __restrict__ deg,
                                              float* __restrict__ dinv) {
    int i = blockIdx.x * 256 + threadIdx.x;   // over 2*N_NODES
    dinv[i] = 1.0f / sqrtf((float)deg[i] + 1.0f);
}

// ---- parallel 2-level exclusive scan of deg -> off ----
__global__ __launch_bounds__(256) void blocksum_k(const int* __restrict__ deg,
                                                  int* __restrict__ bs) {
    int m = blockIdx.y, blk = blockIdx.x, t = threadIdx.x;
    __shared__ int sh[256];
    sh[t] = deg[m * N_NODES + blk * 256 + t];
    __syncthreads();
    for (int ofs = 128; ofs > 0; ofs >>= 1) {
        if (t < ofs) sh[t] += sh[t + ofs];
        __syncthreads();
    }
    if (t == 0) bs[m * 256 + blk] = sh[0];
}

__global__ __launch_bounds__(256) void scan_bs_k(int* __restrict__ bs) {
    int m = blockIdx.x, t = threadIdx.x;
    __shared__ int sh[256];
    sh[t] = bs[m * 256 + t];
    __syncthreads();
    for (int ofs = 1; ofs < 256; ofs <<= 1) {
        int v = sh[t];
        int a = (t >= ofs) ? sh[t - ofs] : 0;
        __syncthreads();
        sh[t] = v + a;
        __syncthreads();
    }
    bs[m * 256 + t] = (t == 0) ? 0 : sh[t - 1];   // exclusive
}

__global__ __launch_bounds__(256) void scan_off_k(const int* __restrict__ deg,
                                                  const int* __restrict__ bs,
                                                  int* __restrict__ off) {
    int m = blockIdx.y, blk = blockIdx.x, t = threadIdx.x;
    int i = blk * 256 + t;
    int d = deg[m * N_NODES + i];
    __shared__ int sh[256];
    sh[t] = d;
    __syncthreads();
    for (int ofs = 1; ofs < 256; ofs <<= 1) {
        int v = sh[t];
        int a = (t >= ofs) ? sh[t - ofs] : 0;
        __syncthreads();
        sh[t] = v + a;
        __syncthreads();
    }
    off[m * OFF_STRIDE + i] = bs[m * 256 + blk] + sh[t] - d;  // exclusive
    if (i == N_NODES - 1) off[m * OFF_STRIDE + N_NODES] = N_EDGES;
}

// ---- CSR fill: 2B src-only entry (norm folded into node scaling) ----
__global__ __launch_bounds__(256) void fill_k(const int* __restrict__ ei,
                                              const int* __restrict__ off,
                                              int* __restrict__ cursor,
                                              unsigned short* __restrict__ csr_src) {
    int e = blockIdx.x * 256 + threadIdx.x;
    int m = blockIdx.y;
    int src = ei[(size_t)(m * 2 + 0) * N_EDGES + e] & NODE_MASK;
    int dst = ei[(size_t)(m * 2 + 1) * N_EDGES + e] & NODE_MASK;
    int pos = off[m * OFF_STRIDE + dst] + atomicAdd(&cursor[m * N_NODES + dst], 1);
    csr_src[(size_t)m * N_EDGES + pos] = (unsigned short)src;
}

// ---------- per-layer GEMM via MFMA, split-fp16; epilogue scales by dinv -----
// tbuf[n] = fp16( dinv[n] * (h @ W)[n] )
__device__ __forceinline__ void split8(const float* p, f16x8& hi, f16x8& lo) {
    float4 a = *(const float4*)p;
    float4 b = *(const float4*)(p + 4);
    float v[8] = {a.x, a.y, a.z, a.w, b.x, b.y, b.z, b.w};
    #pragma unroll
    for (int i = 0; i < 8; i++) {
        f16 h = (f16)v[i];
        hi[i] = h;
        lo[i] = (f16)(v[i] - (float)h);
    }
}

__global__ __launch_bounds__(256) void gemm_mfma_k(const float* __restrict__ h,
                                                   const float* __restrict__ Wall,
                                                   const float* __restrict__ dinv,
                                                   __half* __restrict__ hw, int layer) {
    int m = blockIdx.y;
    const float* Wg = Wall + (size_t)(m * N_LAYERS + layer) * D * D;
    __shared__ __align__(16) _Float16 Whi[D][72];
    __shared__ __align__(16) _Float16 Wlo[D][72];
    for (int idx = threadIdx.x; idx < D * D / 4; idx += 256) {
        float4 v = ((const float4*)Wg)[idx];
        int k  = idx >> 4;
        int c0 = (idx & 15) << 2;
        float vv[4] = {v.x, v.y, v.z, v.w};
        #pragma unroll
        for (int i = 0; i < 4; i++) {
            f16 hi = (f16)vv[i];
            Whi[c0 + i][k] = hi;
            Wlo[c0 + i][k] = (f16)(vv[i] - (float)hi);
        }
    }
    __syncthreads();

    int lane = threadIdx.x & 63;
    int wav  = threadIdx.x >> 6;
    int nn   = lane & 15;
    int quad = lane >> 4;

    f16x8 Bh[8], Bl[8];
    #pragma unroll
    for (int t = 0; t < 4; t++)
        #pragma unroll
        for (int s = 0; s < 2; s++) {
            Bh[t * 2 + s] = *(const f16x8*)&Whi[t * 16 + nn][s * 32 + quad * 8];
            Bl[t * 2 + s] = *(const f16x8*)&Wlo[t * 16 + nn][s * 32 + quad * 8];
        }

    const float* hm = h + (size_t)m * N_NODES * D;
    const float* dm = dinv + m * N_NODES;
    __half*      om = hw + (size_t)m * N_NODES * D;
    int base = blockIdx.x * 256 + wav * 64;
    for (int g = 0; g < 4; g++) {
        int n0 = base + g * 16;
        const float* hrow = hm + (size_t)(n0 + nn) * D;
        f16x8 ah[2], al[2];
        split8(hrow + quad * 8,      ah[0], al[0]);
        split8(hrow + 32 + quad * 8, ah[1], al[1]);
        float dvr[4];
        #pragma unroll
        for (int r = 0; r < 4; r++) dvr[r] = dm[n0 + quad * 4 + r];
        #pragma unroll
        for (int t = 0; t < 4; t++) {
            f32x4 c = {0.f, 0.f, 0.f, 0.f};
            #pragma unroll
            for (int s = 0; s < 2; s++) {
                c = __builtin_amdgcn_mfma_f32_16x16x32_f16(ah[s], Bh[t*2+s], c, 0, 0, 0);
                c = __builtin_amdgcn_mfma_f32_16x16x32_f16(al[s], Bh[t*2+s], c, 0, 0, 0);
                c = __builtin_amdgcn_mfma_f32_16x16x32_f16(ah[s], Bl[t*2+s], c, 0, 0, 0);
            }
            #pragma unroll
            for (int r = 0; r < 4; r++)
                om[(size_t)(n0 + quad * 4 + r) * D + t * 16 + nn] =
                    __float2half((float)c[r] * dvr[r]);
        }
    }
}

// ---------- per-layer aggregate: prescaled rows, 2B edges, 4 edges/gather ----
// out[n] = dinv[n] * (sum_{s in N(n)} hws[s] + hws[n]) + b   [; relu]
__device__ __forceinline__ float4 cvt4(ushort4 u) {
    union { ushort2 us[2]; __half2 h2[2]; } c;
    c.us[0] = make_ushort2(u.x, u.y);
    c.us[1] = make_ushort2(u.z, u.w);
    float2 a = __half22float2(c.h2[0]);
    float2 b = __half22float2(c.h2[1]);
    return make_float4(a.x, a.y, b.x, b.y);
}

__global__ __launch_bounds__(256) void aggregate_k(const __half* __restrict__ hw,
                                                   float* __restrict__ out,
                                                   const int* __restrict__ off,
                                                   const unsigned short* __restrict__ csr_src,
                                                   const float* __restrict__ dinv,
                                                   const float* __restrict__ ball,
                                                   int layer, int relu) {
    int m = blockIdx.y;
    int n = blockIdx.x * 4 + (threadIdx.x >> 6);
    int lane = threadIdx.x & 63;
    int fg   = lane & 15;
    int sub  = lane >> 4;
    const ushort4*        hm4 = (const ushort4*)(hw + (size_t)m * N_NODES * D);
    const int*            ob  = off + m * OFF_STRIDE;
    const unsigned short* sb  = csr_src + (size_t)m * N_EDGES;

    float4 acc = make_float4(0.f, 0.f, 0.f, 0.f);
    int e0 = ob[n], e1 = ob[n + 1];
    #pragma unroll 2
    for (int e = e0; e < e1; e += 4) {
        int ee  = e + sub;
        int idx = (ee < e1) ? ee : (e1 - 1);
        int s   = sb[idx];
        float w = (ee < e1) ? 1.0f : 0.0f;
        float4 g = cvt4(hm4[(size_t)s * 16 + fg]);
        acc.x = fmaf(w, g.x, acc.x);
        acc.y = fmaf(w, g.y, acc.y);
        acc.z = fmaf(w, g.z, acc.z);
        acc.w = fmaf(w, g.w, acc.w);
    }
    #pragma unroll
    for (int msk = 16; msk < 64; msk <<= 1) {
        acc.x += __shfl_xor(acc.x, msk);
        acc.y += __shfl_xor(acc.y, msk);
        acc.z += __shfl_xor(acc.z, msk);
        acc.w += __shfl_xor(acc.w, msk);
    }

    float dv  = dinv[m * N_NODES + n];
    float4 s4 = cvt4(hm4[(size_t)n * 16 + fg]);   // hws[n] (prescaled)
    float4 bi = ((const float4*)(ball + (size_t)(m * N_LAYERS + layer) * D))[fg];
    acc.x = fmaf(dv, acc.x + s4.x, bi.x);
    acc.y = fmaf(dv, acc.y + s4.y, bi.y);
    acc.z = fmaf(dv, acc.z + s4.z, bi.z);
    acc.w = fmaf(dv, acc.w + s4.w, bi.w);
    if (relu) {
        acc.x = fmaxf(acc.x, 0.f);
        acc.y = fmaxf(acc.y, 0.f);
        acc.z = fmaxf(acc.z, 0.f);
        acc.w = fmaxf(acc.w, 0.f);
    }
    if (lane < 16)
        ((float4*)(out + (size_t)m * N_NODES * D + (size_t)n * D))[lane] = acc;
}

// ---------- host ----------

extern "C" void kernel_launch(void* const* d_in, const int* in_sizes, int n_in,
                              void* d_out, int out_size, void* d_ws, size_t ws_size,
                              hipStream_t stream) {
    (void)in_sizes; (void)n_in; (void)out_size; (void)ws_size;
    const float* x  = (const float*)d_in[0];
    const int*   ei = (const int*)d_in[1];
    const float* W  = (const float*)d_in[2];
    const float* b  = (const float*)d_in[3];
    float* out = (float*)d_out;

    char* ws = (char*)d_ws;
    size_t o = 0;
    auto take = [&](size_t bytes) -> void* {
        void* p = ws + o;
        o = (o + bytes + 255) & ~(size_t)255;
        return p;
    };
    int*            deg     = (int*)   take((size_t)N_MEMBERS * N_NODES * 4);
    int*            cursor  = (int*)   take((size_t)N_MEMBERS * N_NODES * 4);
    float*          dinv    = (float*) take((size_t)N_MEMBERS * N_NODES * 4);
    int*            off     = (int*)   take((size_t)N_MEMBERS * OFF_STRIDE * 4);
    int*            bs      = (int*)   take((size_t)N_MEMBERS * 256 * 4);
    unsigned short* csr_src = (unsigned short*)take((size_t)N_MEMBERS * N_EDGES * 2);
    __half*         tbuf    = (__half*)take((size_t)N_MEMBERS * N_NODES * D * 2);
    float*          hbuf    = (float*) take((size_t)N_MEMBERS * N_NODES * D * 4);

    // zero deg + cursor (adjacent, both 256-padded)
    hipMemsetAsync(deg, 0, 2 * (size_t)N_MEMBERS * N_NODES * 4, stream);

    count_deg_k<<<dim3(N_EDGES / 256, N_MEMBERS), 256, 0, stream>>>(ei, deg);
    dinv_k<<<dim3((N_MEMBERS * N_NODES) / 256), 256, 0, stream>>>(deg, dinv);
    blocksum_k<<<dim3(N_NODES / 256, N_MEMBERS), 256, 0, stream>>>(deg, bs);
    scan_bs_k<<<dim3(N_MEMBERS), 256, 0, stream>>>(bs);
    scan_off_k<<<dim3(N_NODES / 256, N_MEMBERS), 256, 0, stream>>>(deg, bs, off);
    fill_k<<<dim3(N_EDGES / 256, N_MEMBERS), 256, 0, stream>>>(ei, off, cursor, csr_src);

    const float* hin = x;
    for (int j = 0; j < N_LAYERS; j++) {
        gemm_mfma_k<<<dim3(N_NODES / 256, N_MEMBERS), 256, 0, stream>>>(hin, W, dinv, tbuf, j);
        float* dst = (j == N_LAYERS - 1) ? out : hbuf;
        aggregate_k<<<dim3(N_NODES / 4, N_MEMBERS), 256, 0, stream>>>(
            tbuf, dst, off, csr_src, dinv, b, j, (j < N_LAYERS - 1) ? 1 : 0);
        hin = hbuf;
    }
}